// Round 4
// baseline (7780.050 us; speedup 1.0000x reference)
//
#include <hip/hip_runtime.h>
#include <hip/hip_bf16.h>

using bf16 = __hip_bfloat16;

constexpr int kH  = 32;    // hidden
constexpr int kE  = 64;    // embed
constexpr int kV  = 258;   // vocab
constexpr int kB  = 16;    // batch
constexpr int kR  = 64;    // rows
constexpr int kS  = 64;    // cols
constexpr int kG  = 96;    // 3*H
constexpr int kEP = 65;    // E+1

// ---------------- workspace layout ----------------
// Region 0: GRU outputs as bf16 [3][16][64][64][32] -> 6,291,456 bf16 = 3,145,728 float slots
constexpr int H2_OFF   = (3*kB*kR*kS*kH)/2;           // fp32 [16][64][32] in-row layer2 state
constexpr int T_OFF    = H2_OFF + kB*kR*kH;           // [3][258][96]  emb@Wih0[:, :64].T
constexpr int WPH_OFF  = T_OFF + 3*kV*kG;             // [3][96][32]   Wih0 @ h2e_W  fold
constexpr int WADP_OFF = WPH_OFF + 3*kG*kH;           // [2][96][32]   Wih0 @ adp_W  fold
constexpr int C0_OFF   = WADP_OFF + 2*kG*kH;          // [3][96]       bih0 + h2e_b/adp_b folds
constexpr int RW_OFF   = C0_OFF + 3*kG;               // [3][96]       Wih0[:,64] (row-feat col)
constexpr int TG_OFF   = RW_OFF + 3*kG;               // [258][258]    emb0 @ green_W[:,32:96].T
constexpr int TBR_OFF  = TG_OFF + kV*kV;              // [258][258]    emb0 @ blue_W[:,32:96].T
constexpr int TBG_OFF  = TBR_OFF + kV*kV;             // [258][258]    emb1 @ blue_W[:,96:160].T
// normalized fp32 parameter copies (dtype-detected at runtime)
constexpr int P_EMB    = TBG_OFF + kV*kV;
constexpr int P_WIH0   = P_EMB    + 3*kV*kE;
constexpr int P_WIHR   = P_WIH0   + 3*kG*kEP;
constexpr int P_WHH    = P_WIHR   + 3*2*kG*kH;
constexpr int P_BIH    = P_WHH    + 3*3*kG*kH;
constexpr int P_BHH    = P_BIH    + 3*3*kG;
constexpr int P_H2EW   = P_BHH    + 3*3*kG;
constexpr int P_H2EB   = P_H2EW   + 3*kEP*kH;
constexpr int P_ADPW   = P_H2EB   + 3*kEP;
constexpr int P_ADPB   = P_ADPW   + 2*kEP*kH;
constexpr int P_REDW   = P_ADPB   + 2*kEP;
constexpr int P_REDB   = P_REDW   + kV*kH;
constexpr int P_GREENW = P_REDB   + kV;
constexpr int P_GREENB = P_GREENW + kV*(kH+kE);
constexpr int P_BLUEW  = P_GREENB + kV;
constexpr int P_BLUEB  = P_BLUEW  + kV*(kH+2*kE);
constexpr int WS_END   = P_BLUEB  + kV;               // ~3.67M floats = ~14.0 MB

__device__ __forceinline__ float tof(bf16 h) { return __bfloat162float(h); }

__device__ __forceinline__ unsigned short bfbits(bf16 h) {
  union { bf16 h; unsigned short u; } cv; cv.h = h; return cv.u;
}

__device__ __forceinline__ unsigned int pack_bf2(float a, float b) {
  return (unsigned int)bfbits(__float2bfloat16(a)) |
         ((unsigned int)bfbits(__float2bfloat16(b)) << 16);
}

__device__ __forceinline__ float2 bf2x2(unsigned int w) {
  float2 r;
  r.x = __uint_as_float(w << 16);
  r.y = __uint_as_float(w & 0xffff0000u);
  return r;
}

__device__ __forceinline__ float sigm(float v) { return 1.0f / (1.0f + __expf(-v)); }
__device__ __forceinline__ float tanh_(float v) { return 1.0f - 2.0f / (__expf(2.0f * v) + 1.0f); }

// dot of a 32-wide weight row (bf16 pairs, XOR-pair-swizzled) with a bf16 vec (pairs) or fp32 vec
__device__ __forceinline__ float dot_bfvec(const unsigned int* wrow, int rx, const unsigned int* v) {
  float acc = 0.f;
#pragma unroll
  for (int p = 0; p < 16; ++p) {
    float2 w = bf2x2(wrow[p ^ rx]);
    float2 xv = bf2x2(v[p]);
    acc = fmaf(w.x, xv.x, acc);
    acc = fmaf(w.y, xv.y, acc);
  }
  return acc;
}

__device__ __forceinline__ float dot_f32vec(const unsigned int* wrow, int rx, const float* v) {
  float acc = 0.f;
#pragma unroll
  for (int p = 0; p < 16; ++p) {
    float2 w = bf2x2(wrow[p ^ rx]);
    acc = fmaf(w.x, v[2*p], acc);
    acc = fmaf(w.y, v[2*p+1], acc);
  }
  return acc;
}

// ---------------- dtype detect + normalize to fp32 ----------------
// One block per float-typed input array. Sample first <=2048 uint16s; genuine
// bf16 data (0.15*normal) never has bf16-exponent-field >= 135; f32 storage
// exposes uniform-random mantissa halves which do (P_miss < 1e-18).
// R1->R2 transition proved inputs are f32-stored; this stays as cheap insurance.
__global__ void norm_kernel(const void* p0, const void* p1, const void* p2, const void* p3,
                            const void* p4, const void* p5, const void* p6, const void* p7,
                            const void* p8, const void* p9, const void* p10, const void* p11,
                            const void* p12, const void* p13, const void* p14, const void* p15,
                            float* __restrict__ wsf)
{
  constexpr int counts[16] = {3*kV*kE, 3*kG*kEP, 3*2*kG*kH, 3*3*kG*kH, 3*3*kG, 3*3*kG,
                              3*kEP*kH, 3*kEP, 2*kEP*kH, 2*kEP, kV*kH, kV,
                              kV*(kH+kE), kV, kV*(kH+2*kE), kV};
  constexpr int dsts[16] = {P_EMB, P_WIH0, P_WIHR, P_WHH, P_BIH, P_BHH,
                            P_H2EW, P_H2EB, P_ADPW, P_ADPB, P_REDW, P_REDB,
                            P_GREENW, P_GREENB, P_BLUEW, P_BLUEB};
  const void* srcs[16] = {p0,p1,p2,p3,p4,p5,p6,p7,p8,p9,p10,p11,p12,p13,p14,p15};

  __shared__ unsigned int smax;
  const int a = blockIdx.x;
  const void* src = srcs[a];
  const int n = counts[a];
  if (threadIdx.x == 0) smax = 0;
  __syncthreads();

  const unsigned short* u16 = (const unsigned short*)src;
  const int ns = (n < 2048) ? n : 2048;
  unsigned int lm = 0;
  for (int i = threadIdx.x; i < ns; i += 256) {
    unsigned int e = ((unsigned int)u16[i] >> 7) & 0xFFu;
    if (e > lm) lm = e;
  }
  atomicMax(&smax, lm);
  __syncthreads();

  const bool isf32 = (smax >= 135);
  float* dst = wsf + dsts[a];
  if (isf32) {
    const float* s = (const float*)src;
    for (int i = threadIdx.x; i < n; i += 256) dst[i] = s[i];
  } else {
    const bf16* s = (const bf16*)src;
    for (int i = threadIdx.x; i < n; i += 256) dst[i] = tof(s[i]);
  }
}

// ---------------- prep: fold tables & matrices (reads normalized fp32) ----------------
__global__ void prep_kernel(float* __restrict__ wsf)
{
  int idx = blockIdx.x * 256 + threadIdx.x;

  if (idx < 3*kV*kG) {  // T[c][v][j] = sum_e emb[c][v][e] * Wih0[c][j][e]
    int c = idx / (kV*kG);
    int rem = idx - c*(kV*kG);
    int v = rem / kG;
    int j = rem - v*kG;
    const float* ev = wsf + P_EMB + (c*kV + v)*kE;
    const float* wr = wsf + P_WIH0 + (c*kG + j)*kEP;
    float acc = 0.f;
    for (int e = 0; e < kE; ++e) acc = fmaf(ev[e], wr[e], acc);
    wsf[T_OFF + idx] = acc;
    return;
  }
  idx -= 3*kV*kG;

  if (idx < 3*kG*kH) {  // Wph[c][j][k] = sum_e Wih0[c][j][e] * h2e_W[c][e][k]  (e over all 65)
    int c = idx / (kG*kH);
    int rem = idx - c*(kG*kH);
    int j = rem >> 5;
    int k = rem & 31;
    const float* wr = wsf + P_WIH0 + (c*kG + j)*kEP;
    const float* hw = wsf + P_H2EW + c*kEP*kH + k;
    float acc = 0.f;
    for (int e = 0; e < kEP; ++e) acc = fmaf(wr[e], hw[e*kH], acc);
    wsf[WPH_OFF + idx] = acc;
    return;
  }
  idx -= 3*kG*kH;

  if (idx < 2*kG*kH) {  // Wadp[cm][j][k] = sum_e Wih0[cm+1][j][e] * adp_W[cm][e][k]
    int cm = idx / (kG*kH);
    int rem = idx - cm*(kG*kH);
    int j = rem >> 5;
    int k = rem & 31;
    const float* wr = wsf + P_WIH0 + ((cm+1)*kG + j)*kEP;
    const float* aw = wsf + P_ADPW + cm*kEP*kH + k;
    float acc = 0.f;
    for (int e = 0; e < kEP; ++e) acc = fmaf(wr[e], aw[e*kH], acc);
    wsf[WADP_OFF + idx] = acc;
    return;
  }
  idx -= 2*kG*kH;

  if (idx < 3*kG) {  // const0[c][j] = bih0 + h2e_b fold (+ adp_b fold for c>0)
    int c = idx / kG;
    int j = idx - c*kG;
    const float* wr = wsf + P_WIH0 + (c*kG + j)*kEP;
    float acc = wsf[P_BIH + (c*3 + 0)*kG + j];
    for (int e = 0; e < kEP; ++e) acc = fmaf(wsf[P_H2EB + c*kEP + e], wr[e], acc);
    if (c > 0)
      for (int e = 0; e < kEP; ++e) acc = fmaf(wsf[P_ADPB + (c-1)*kEP + e], wr[e], acc);
    wsf[C0_OFF + idx] = acc;
    return;
  }
  idx -= 3*kG;

  if (idx < 3*kG) {  // rowW[c][j] = Wih0[c][j][64]
    int c = idx / kG;
    int j = idx - c*kG;
    wsf[RW_OFF + idx] = wsf[P_WIH0 + (c*kG + j)*kEP + kE];
    return;
  }
  idx -= 3*kG;

  if (idx < kV*kV) {  // TG[v][w] = emb0[v] . green_W[w][32:96]
    int v = idx / kV, w = idx - (idx / kV)*kV;
    const float* ev = wsf + P_EMB + v*kE;
    const float* gw = wsf + P_GREENW + w*(kH + kE) + kH;
    float acc = 0.f;
    for (int e = 0; e < kE; ++e) acc = fmaf(ev[e], gw[e], acc);
    wsf[TG_OFF + idx] = acc;
    return;
  }
  idx -= kV*kV;

  if (idx < kV*kV) {  // TBR[v][w] = emb0[v] . blue_W[w][32:96]
    int v = idx / kV, w = idx - (idx / kV)*kV;
    const float* ev = wsf + P_EMB + v*kE;
    const float* bw = wsf + P_BLUEW + w*(kH + 2*kE) + kH;
    float acc = 0.f;
    for (int e = 0; e < kE; ++e) acc = fmaf(ev[e], bw[e], acc);
    wsf[TBR_OFF + idx] = acc;
    return;
  }
  idx -= kV*kV;

  if (idx < kV*kV) {  // TBG[v][w] = emb1[v] . blue_W[w][96:160]
    int v = idx / kV, w = idx - (idx / kV)*kV;
    const float* ev = wsf + P_EMB + (kV + v)*kE;
    const float* bw = wsf + P_BLUEW + w*(kH + 2*kE) + kH + kE;
    float acc = 0.f;
    for (int e = 0; e < kE; ++e) acc = fmaf(ev[e], bw[e], acc);
    wsf[TBG_OFF + idx] = acc;
  }
}

// ---------------- per-channel wavefront recurrence ----------------
// grid = 16 (one WG per batch), block = 512 = 16 cell-slots x 32 lanes.
// Diagonal d: cells (r, s=d-r). Outputs stored bf16; in-row layer2 state fp32 in H2BUF.
template<int C>
__global__ __launch_bounds__(512)
void recur_kernel(const int* __restrict__ x, float* __restrict__ wsf)
{
  constexpr int NM = (C == 0) ? 6 : 7;  // 0:Wph 1:Whh0 2:Wih1 3:Whh1 4:Wih2 5:Whh2 [6:Wadp]
  __shared__ unsigned int wmat[NM][kG][16];
  __shared__ float hstate[kR][2][kH];
  __shared__ alignas(16) bf16 stg_ph[16][kH];
  __shared__ alignas(16) bf16 stg_po[16][kH];
  __shared__ alignas(16) float stg_h2[16][kH];

  const int b = blockIdx.x;
  const int tid = threadIdx.x;
  const int cs = tid >> 5;
  const int li = tid & 31;

  // build weight LDS (bf16 pairs, pair index XOR-swizzled by row&15 -> <=2-way bank aliasing)
  for (int w = tid; w < NM*kG*16; w += 512) {
    int mat = w / (kG*16);
    int rem = w - mat*(kG*16);
    int row = rem >> 4;
    int p = rem & 15;
    const float* s;
    if (mat == 0)      s = wsf + WPH_OFF + (C*kG + row)*kH + 2*p;
    else if (mat == 1) s = wsf + P_WHH  + ((C*3 + 0)*kG + row)*kH + 2*p;
    else if (mat == 2) s = wsf + P_WIHR + ((C*2 + 0)*kG + row)*kH + 2*p;
    else if (mat == 3) s = wsf + P_WHH  + ((C*3 + 1)*kG + row)*kH + 2*p;
    else if (mat == 4) s = wsf + P_WIHR + ((C*2 + 1)*kG + row)*kH + 2*p;
    else if (mat == 5) s = wsf + P_WHH  + ((C*3 + 2)*kG + row)*kH + 2*p;
    else               s = wsf + WADP_OFF + ((C-1)*kG + row)*kH + 2*p;
    wmat[mat][row][p ^ (row & 15)] = pack_bf2(s[0], s[1]);
  }
  for (int w = tid; w < kR*2*kH; w += 512) (&hstate[0][0][0])[w] = 0.f;

  const int jr = li, jz = kH + li, jn = 2*kH + li;
  const float c0r = wsf[C0_OFF + C*kG + jr];
  const float c0z = wsf[C0_OFF + C*kG + jz];
  const float c0n = wsf[C0_OFF + C*kG + jn];
  const float rwr = wsf[RW_OFF + C*kG + jr];
  const float rwz = wsf[RW_OFF + C*kG + jz];
  const float rwn = wsf[RW_OFF + C*kG + jn];
  const float bh0r = wsf[P_BHH + (C*3+0)*kG + jr];
  const float bh0z = wsf[P_BHH + (C*3+0)*kG + jz];
  const float bh0n = wsf[P_BHH + (C*3+0)*kG + jn];
  const float bi1r = wsf[P_BIH + (C*3+1)*kG + jr];
  const float bi1z = wsf[P_BIH + (C*3+1)*kG + jz];
  const float bi1n = wsf[P_BIH + (C*3+1)*kG + jn];
  const float bh1r = wsf[P_BHH + (C*3+1)*kG + jr];
  const float bh1z = wsf[P_BHH + (C*3+1)*kG + jz];
  const float bh1n = wsf[P_BHH + (C*3+1)*kG + jn];
  const float bi2r = wsf[P_BIH + (C*3+2)*kG + jr];
  const float bi2z = wsf[P_BIH + (C*3+2)*kG + jz];
  const float bi2n = wsf[P_BIH + (C*3+2)*kG + jn];
  const float bh2r = wsf[P_BHH + (C*3+2)*kG + jr];
  const float bh2z = wsf[P_BHH + (C*3+2)*kG + jz];
  const float bh2n = wsf[P_BHH + (C*3+2)*kG + jn];

  bf16* outsB = (bf16*)wsf;
  bf16* outsC = outsB + (size_t)(C*kB + b) * (kR*kS*kH);
  const bf16* outsP = (C > 0) ? (outsB + (size_t)((C-1)*kB + b) * (kR*kS*kH)) : outsC;
  float* h2buf = wsf + H2_OFF + b*kR*kH;
  const bf16 z16 = __float2bfloat16(0.f);
  const int rx = li & 15;  // (32+li)&15 == (64+li)&15 == li&15
  __syncthreads();

  for (int d = 0; d < kR + kS - 1; ++d) {
    const int rlo = (d > kS-1) ? (d - (kS-1)) : 0;
    const int rhi = (d < kR-1) ? d : kR-1;
    for (int cb = rlo; cb <= rhi; cb += 16) {
      const int r = cb + cs;
      const int s = d - r;
      const bool act = (r <= rhi);

      bf16 phv = z16, pov = z16;
      float h2v = 0.f;
      if (act) {
        if (r > 0) phv = outsC[((r-1)*kS + s)*kH + li];
        if (C > 0) pov = outsP[(r*kS + s)*kH + li];
        if (s > 0) h2v = h2buf[r*kH + li];
      }
      stg_ph[cs][li] = phv;
      if (C > 0) stg_po[cs][li] = pov;
      stg_h2[cs][li] = h2v;
      __syncthreads();

      // ---- layer 0 ----
      float h0new = 0.f;
      if (act) {
        const int xi = x[((b*3 + C)*kR + r)*kS + s];
        const float rp = (float)r * (2.0f / (float)kR) - 1.0f;
        const float* Trow = wsf + T_OFF + (C*kV + xi)*kG;
        const unsigned int* phu = (const unsigned int*)(&stg_ph[cs][0]);
        float gir = Trow[jr] + rp*rwr + c0r + dot_bfvec(wmat[0][jr], rx, phu);
        float giz = Trow[jz] + rp*rwz + c0z + dot_bfvec(wmat[0][jz], rx, phu);
        float gin = Trow[jn] + rp*rwn + c0n + dot_bfvec(wmat[0][jn], rx, phu);
        if (C > 0) {
          const unsigned int* pou = (const unsigned int*)(&stg_po[cs][0]);
          gir += dot_bfvec(wmat[NM-1][jr], rx, pou);
          giz += dot_bfvec(wmat[NM-1][jz], rx, pou);
          gin += dot_bfvec(wmat[NM-1][jn], rx, pou);
        }
        const float* h0 = &hstate[r][0][0];
        float ghr = bh0r + dot_f32vec(wmat[1][jr], rx, h0);
        float ghz = bh0z + dot_f32vec(wmat[1][jz], rx, h0);
        float ghn = bh0n + dot_f32vec(wmat[1][jn], rx, h0);
        float rg = sigm(gir + ghr);
        float zg = sigm(giz + ghz);
        float ng = tanh_(gin + rg*ghn);
        h0new = (1.f - zg)*ng + zg*h0[li];
      }
      __syncthreads();
      if (act) hstate[r][0][li] = h0new;
      __syncthreads();

      // ---- layer 1 ----
      float h1new = 0.f;
      if (act) {
        const float* h0 = &hstate[r][0][0];
        const float* h1 = &hstate[r][1][0];
        float gir = bi1r + dot_f32vec(wmat[2][jr], rx, h0);
        float giz = bi1z + dot_f32vec(wmat[2][jz], rx, h0);
        float gin = bi1n + dot_f32vec(wmat[2][jn], rx, h0);
        float ghr = bh1r + dot_f32vec(wmat[3][jr], rx, h1);
        float ghz = bh1z + dot_f32vec(wmat[3][jz], rx, h1);
        float ghn = bh1n + dot_f32vec(wmat[3][jn], rx, h1);
        float rg = sigm(gir + ghr);
        float zg = sigm(giz + ghz);
        float ng = tanh_(gin + rg*ghn);
        h1new = (1.f - zg)*ng + zg*h1[li];
      }
      __syncthreads();
      if (act) hstate[r][1][li] = h1new;
      __syncthreads();

      // ---- layer 2 (output) ----
      if (act) {
        const float* h1 = &hstate[r][1][0];
        const float* h2 = &stg_h2[cs][0];
        float gir = bi2r + dot_f32vec(wmat[4][jr], rx, h1);
        float giz = bi2z + dot_f32vec(wmat[4][jz], rx, h1);
        float gin = bi2n + dot_f32vec(wmat[4][jn], rx, h1);
        float ghr = bh2r + dot_f32vec(wmat[5][jr], rx, h2);
        float ghz = bh2z + dot_f32vec(wmat[5][jz], rx, h2);
        float ghn = bh2n + dot_f32vec(wmat[5][jn], rx, h2);
        float rg = sigm(gir + ghr);
        float zg = sigm(giz + ghz);
        float ng = tanh_(gin + rg*ghn);
        float h2new = (1.f - zg)*ng + zg*h2[li];
        outsC[(r*kS + s)*kH + li] = __float2bfloat16(h2new);
        h2buf[r*kH + li] = h2new;
      }
      __syncthreads();
    }
  }
}

// ---------------- logits epilogue (fp32 output — reference output dtype) ----------------
__global__ void logits_kernel(const int* __restrict__ target, const float* __restrict__ wsf,
                              float* __restrict__ out)
{
  int idx = blockIdx.x * 256 + threadIdx.x;
  if (idx >= 3*kB*kR*kS*kV) return;
  int v = idx % kV;
  int pos = idx / kV;        // (b*3+ch)*4096 + r*64 + s
  int g = pos >> 12;
  int ch = g % 3;
  int b = g / 3;
  int rs = pos & 4095;
  const bf16* hv = (const bf16*)wsf + ((size_t)(ch*kB + b)*4096 + rs)*kH;
  float acc;
  const float* wv;
  if (ch == 0) {
    acc = wsf[P_REDB + v];
    wv = wsf + P_REDW + v*kH;
  } else if (ch == 1) {
    int tr = target[(b*3 + 0)*4096 + rs];
    acc = wsf[P_GREENB + v] + wsf[TG_OFF + tr*kV + v];
    wv = wsf + P_GREENW + v*(kH + kE);
  } else {
    int tr = target[(b*3 + 0)*4096 + rs];
    int tg = target[(b*3 + 1)*4096 + rs];
    acc = wsf[P_BLUEB + v] + wsf[TBR_OFF + tr*kV + v] + wsf[TBG_OFF + tg*kV + v];
    wv = wsf + P_BLUEW + v*(kH + 2*kE);
  }
#pragma unroll
  for (int k = 0; k < kH; ++k) acc = fmaf(wv[k], tof(hv[k]), acc);
  out[idx] = acc;
}

extern "C" void kernel_launch(void* const* d_in, const int* in_sizes, int n_in,
                              void* d_out, int out_size, void* d_ws, size_t ws_size,
                              hipStream_t stream)
{
  const int* x      = (const int*)d_in[0];
  const int* target = (const int*)d_in[1];
  float* wsf = (float*)d_ws;

  norm_kernel<<<16, 256, 0, stream>>>(d_in[2], d_in[3], d_in[4], d_in[5], d_in[6], d_in[7],
                                      d_in[8], d_in[9], d_in[10], d_in[11], d_in[12], d_in[13],
                                      d_in[14], d_in[15], d_in[16], d_in[17], wsf);
  const int prepN = 3*kV*kG + 3*kG*kH + 2*kG*kH + 3*kG + 3*kG + 3*kV*kV;
  prep_kernel<<<(prepN + 255)/256, 256, 0, stream>>>(wsf);
  recur_kernel<0><<<kB, 512, 0, stream>>>(x, wsf);
  recur_kernel<1><<<kB, 512, 0, stream>>>(x, wsf);
  recur_kernel<2><<<kB, 512, 0, stream>>>(x, wsf);
  const int outN = 3*kB*kR*kS*kV;
  logits_kernel<<<(outN + 255)/256, 256, 0, stream>>>(target, wsf, (float*)d_out);
}

// Round 5
// 2447.290 us; speedup vs baseline: 3.1790x; 3.1790x over previous
//
#include <hip/hip_runtime.h>
#include <hip/hip_bf16.h>

using bf16 = __hip_bfloat16;
typedef __attribute__((ext_vector_type(8))) short bfrag;   // 8 bf16 (4 VGPRs)
typedef __attribute__((ext_vector_type(4))) float ffrag;   // 4 fp32 acc

constexpr int kH  = 32;    // hidden
constexpr int kE  = 64;    // embed
constexpr int kV  = 258;   // vocab
constexpr int kB  = 16;    // batch
constexpr int kR  = 64;    // rows
constexpr int kS  = 64;    // cols
constexpr int kG  = 96;    // 3*H
constexpr int kEP = 65;    // E+1

// ---------------- workspace layout ----------------
// Region 0: GRU outputs as bf16 [3][16][64][64][32] = 3,145,728 float slots
constexpr int H2_OFF   = (3*kB*kR*kS*kH)/2;           // hole (old h2buf) -> progress flags
constexpr int PROG_OFF = H2_OFF;                      // 48 ints (channel pipeline progress)
constexpr int T_OFF    = H2_OFF + kB*kR*kH;           // [3][258][96]  emb@Wih0[:, :64].T
constexpr int WPH_OFF  = T_OFF + 3*kV*kG;             // [3][96][32]   Wih0 @ h2e_W  fold
constexpr int WADP_OFF = WPH_OFF + 3*kG*kH;           // [2][96][32]   Wih0 @ adp_W  fold
constexpr int C0_OFF   = WADP_OFF + 2*kG*kH;          // [3][96]
constexpr int RW_OFF   = C0_OFF + 3*kG;               // [3][96]
constexpr int TG_OFF   = RW_OFF + 3*kG;               // [258][258]
constexpr int TBR_OFF  = TG_OFF + kV*kV;              // [258][258]
constexpr int TBG_OFF  = TBR_OFF + kV*kV;             // [258][258]
constexpr int P_EMB    = TBG_OFF + kV*kV;
constexpr int P_WIH0   = P_EMB    + 3*kV*kE;
constexpr int P_WIHR   = P_WIH0   + 3*kG*kEP;
constexpr int P_WHH    = P_WIHR   + 3*2*kG*kH;
constexpr int P_BIH    = P_WHH    + 3*3*kG*kH;
constexpr int P_BHH    = P_BIH    + 3*3*kG;
constexpr int P_H2EW   = P_BHH    + 3*3*kG;
constexpr int P_H2EB   = P_H2EW   + 3*kEP*kH;
constexpr int P_ADPW   = P_H2EB   + 3*kEP;
constexpr int P_ADPB   = P_ADPW   + 2*kEP*kH;
constexpr int P_REDW   = P_ADPB   + 2*kEP;
constexpr int P_REDB   = P_REDW   + kV*kH;
constexpr int P_GREENW = P_REDB   + kV;
constexpr int P_GREENB = P_GREENW + kV*(kH+kE);
constexpr int P_BLUEW  = P_GREENB + kV;
constexpr int P_BLUEB  = P_BLUEW  + kV*(kH+2*kE);
constexpr int WS_END   = P_BLUEB  + kV;               // ~14.0 MB

__device__ __forceinline__ float tof(bf16 h) { return __bfloat162float(h); }

__device__ __forceinline__ unsigned short bfbits(bf16 h) {
  union { bf16 h; unsigned short u; } cv; cv.h = h; return cv.u;
}
__device__ __forceinline__ short f2b(float v) {
  return (short)bfbits(__float2bfloat16(v));
}
__device__ __forceinline__ float sigm(float v) { return 1.0f / (1.0f + __expf(-v)); }
__device__ __forceinline__ float tanh_(float v) { return 1.0f - 2.0f / (__expf(2.0f * v) + 1.0f); }

// ---------------- dtype detect + normalize to fp32 ----------------
__global__ void norm_kernel(const void* p0, const void* p1, const void* p2, const void* p3,
                            const void* p4, const void* p5, const void* p6, const void* p7,
                            const void* p8, const void* p9, const void* p10, const void* p11,
                            const void* p12, const void* p13, const void* p14, const void* p15,
                            float* __restrict__ wsf)
{
  constexpr int counts[16] = {3*kV*kE, 3*kG*kEP, 3*2*kG*kH, 3*3*kG*kH, 3*3*kG, 3*3*kG,
                              3*kEP*kH, 3*kEP, 2*kEP*kH, 2*kEP, kV*kH, kV,
                              kV*(kH+kE), kV, kV*(kH+2*kE), kV};
  constexpr int dsts[16] = {P_EMB, P_WIH0, P_WIHR, P_WHH, P_BIH, P_BHH,
                            P_H2EW, P_H2EB, P_ADPW, P_ADPB, P_REDW, P_REDB,
                            P_GREENW, P_GREENB, P_BLUEW, P_BLUEB};
  const void* srcs[16] = {p0,p1,p2,p3,p4,p5,p6,p7,p8,p9,p10,p11,p12,p13,p14,p15};

  __shared__ unsigned int smax;
  const int a = blockIdx.x;
  const void* src = srcs[a];
  const int n = counts[a];
  if (threadIdx.x == 0) smax = 0;
  // zero the channel-pipeline progress flags (block 0 only)
  if (a == 0) {
    int* prog = (int*)(wsf + PROG_OFF);
    for (int i = threadIdx.x; i < 48; i += 256) prog[i] = 0;
  }
  __syncthreads();

  const unsigned short* u16 = (const unsigned short*)src;
  const int ns = (n < 2048) ? n : 2048;
  unsigned int lm = 0;
  for (int i = threadIdx.x; i < ns; i += 256) {
    unsigned int e = ((unsigned int)u16[i] >> 7) & 0xFFu;
    if (e > lm) lm = e;
  }
  atomicMax(&smax, lm);
  __syncthreads();

  const bool isf32 = (smax >= 135);
  float* dst = wsf + dsts[a];
  if (isf32) {
    const float* s = (const float*)src;
    for (int i = threadIdx.x; i < n; i += 256) dst[i] = s[i];
  } else {
    const bf16* s = (const bf16*)src;
    for (int i = threadIdx.x; i < n; i += 256) dst[i] = tof(s[i]);
  }
}

// ---------------- prep: fold tables & matrices (unchanged, verified) ----------------
__global__ void prep_kernel(float* __restrict__ wsf)
{
  int idx = blockIdx.x * 256 + threadIdx.x;

  if (idx < 3*kV*kG) {
    int c = idx / (kV*kG);
    int rem = idx - c*(kV*kG);
    int v = rem / kG;
    int j = rem - v*kG;
    const float* ev = wsf + P_EMB + (c*kV + v)*kE;
    const float* wr = wsf + P_WIH0 + (c*kG + j)*kEP;
    float acc = 0.f;
    for (int e = 0; e < kE; ++e) acc = fmaf(ev[e], wr[e], acc);
    wsf[T_OFF + idx] = acc;
    return;
  }
  idx -= 3*kV*kG;

  if (idx < 3*kG*kH) {
    int c = idx / (kG*kH);
    int rem = idx - c*(kG*kH);
    int j = rem >> 5;
    int k = rem & 31;
    const float* wr = wsf + P_WIH0 + (c*kG + j)*kEP;
    const float* hw = wsf + P_H2EW + c*kEP*kH + k;
    float acc = 0.f;
    for (int e = 0; e < kEP; ++e) acc = fmaf(wr[e], hw[e*kH], acc);
    wsf[WPH_OFF + idx] = acc;
    return;
  }
  idx -= 3*kG*kH;

  if (idx < 2*kG*kH) {
    int cm = idx / (kG*kH);
    int rem = idx - cm*(kG*kH);
    int j = rem >> 5;
    int k = rem & 31;
    const float* wr = wsf + P_WIH0 + ((cm+1)*kG + j)*kEP;
    const float* aw = wsf + P_ADPW + cm*kEP*kH + k;
    float acc = 0.f;
    for (int e = 0; e < kEP; ++e) acc = fmaf(wr[e], aw[e*kH], acc);
    wsf[WADP_OFF + idx] = acc;
    return;
  }
  idx -= 2*kG*kH;

  if (idx < 3*kG) {
    int c = idx / kG;
    int j = idx - c*kG;
    const float* wr = wsf + P_WIH0 + (c*kG + j)*kEP;
    float acc = wsf[P_BIH + (c*3 + 0)*kG + j];
    for (int e = 0; e < kEP; ++e) acc = fmaf(wsf[P_H2EB + c*kEP + e], wr[e], acc);
    if (c > 0)
      for (int e = 0; e < kEP; ++e) acc = fmaf(wsf[P_ADPB + (c-1)*kEP + e], wr[e], acc);
    wsf[C0_OFF + idx] = acc;
    return;
  }
  idx -= 3*kG;

  if (idx < 3*kG) {
    int c = idx / kG;
    int j = idx - c*kG;
    wsf[RW_OFF + idx] = wsf[P_WIH0 + (c*kG + j)*kEP + kE];
    return;
  }
  idx -= 3*kG;

  if (idx < kV*kV) {
    int v = idx / kV, w = idx - (idx / kV)*kV;
    const float* ev = wsf + P_EMB + v*kE;
    const float* gw = wsf + P_GREENW + w*(kH + kE) + kH;
    float acc = 0.f;
    for (int e = 0; e < kE; ++e) acc = fmaf(ev[e], gw[e], acc);
    wsf[TG_OFF + idx] = acc;
    return;
  }
  idx -= kV*kV;

  if (idx < kV*kV) {
    int v = idx / kV, w = idx - (idx / kV)*kV;
    const float* ev = wsf + P_EMB + v*kE;
    const float* bw = wsf + P_BLUEW + w*(kH + 2*kE) + kH;
    float acc = 0.f;
    for (int e = 0; e < kE; ++e) acc = fmaf(ev[e], bw[e], acc);
    wsf[TBR_OFF + idx] = acc;
    return;
  }
  idx -= kV*kV;

  if (idx < kV*kV) {
    int v = idx / kV, w = idx - (idx / kV)*kV;
    const float* ev = wsf + P_EMB + (kV + v)*kE;
    const float* bw = wsf + P_BLUEW + w*(kH + 2*kE) + kH + kE;
    float acc = 0.f;
    for (int e = 0; e < kE; ++e) acc = fmaf(ev[e], bw[e], acc);
    wsf[TBG_OFF + idx] = acc;
  }
}

// ---------------- fused 3-channel MFMA wavefront recurrence ----------------
// Grid = 48 WGs: wg = c*16 + b. Block = 256 = 4 waves; wave w owns rows [16w,16w+16).
// Diagonal d: cell (r, s=d-r). Channel c runs DELTA diagonals behind c-1; po read
// from global outs of c-1, gated by device-scope progress counters.
// MFMA 16x16x32 bf16: M=16 cells, K=32 hidden, N=6x16 gate tiles.
// A-frag: lane holds A[m=lane&15][k=(lane>>4)*8+j]; B-frag: B[k=(lane>>4)*8+j][n=lane&15];
// C/D: cell=(lane>>4)*4+reg, gatecol=lane&15.
__global__ __launch_bounds__(256, 1)
void recur_all_kernel(const int* __restrict__ x, float* __restrict__ wsf)
{
  const int wg = blockIdx.x;
  const int c  = wg >> 4;
  const int b  = wg & 15;
  const int tid = threadIdx.x;

  __shared__ short h01[kR][2][kH];     // bf16 layer-0/1 hidden state (A-frag source)
  __shared__ short ring[2][kR][kH];    // bf16 prev/cur diagonal layer-2 outputs

  for (int i = tid; i < kR*2*kH; i += 256) (&h01[0][0][0])[i] = 0;
  for (int i = tid; i < 2*kR*kH; i += 256) (&ring[0][0][0])[i] = 0;

  const int w    = tid >> 6;        // wave id: row band
  const int lane = tid & 63;
  const int m    = lane & 15;       // A-frag row / B-frag col
  const int q    = lane >> 4;       // quad
  const int ln   = m;

  // ---- hoist weights into registers as B-fragments (bf16) ----
  // mats: 0:Wph 1:Whh0 2:Wih1 3:Whh1 4:Wih2 5:Whh2 6:Wadp
  const float* wsrc[7];
  wsrc[0] = wsf + WPH_OFF + c*kG*kH;
  wsrc[1] = wsf + P_WHH  + (c*3+0)*kG*kH;
  wsrc[2] = wsf + P_WIHR + (c*2+0)*kG*kH;
  wsrc[3] = wsf + P_WHH  + (c*3+1)*kG*kH;
  wsrc[4] = wsf + P_WIHR + (c*2+1)*kG*kH;
  wsrc[5] = wsf + P_WHH  + (c*3+2)*kG*kH;
  wsrc[6] = (c > 0) ? (wsf + WADP_OFF + (c-1)*kG*kH) : (wsf + WPH_OFF);

  bfrag Wb[7][6];
#pragma unroll
  for (int mt = 0; mt < 7; ++mt) {
#pragma unroll
    for (int u = 0; u < 6; ++u) {
      const float* p = wsrc[mt] + (u*16 + ln)*kH + q*8;
#pragma unroll
      for (int j = 0; j < 8; ++j) Wb[mt][u][j] = f2b(p[j]);
    }
  }

  // per-lane gate-column constants (tile u -> gate g = u*16+ln)
  float c0t[6], rwt[6], bh0t[6], bi1t[6], bh1t[6], bi2t[6], bh2t[6];
#pragma unroll
  for (int u = 0; u < 6; ++u) {
    int g = u*16 + ln;
    c0t[u]  = wsf[C0_OFF + c*kG + g];
    rwt[u]  = wsf[RW_OFF + c*kG + g];
    bh0t[u] = wsf[P_BHH + (c*3+0)*kG + g];
    bi1t[u] = wsf[P_BIH + (c*3+1)*kG + g];
    bh1t[u] = wsf[P_BHH + (c*3+1)*kG + g];
    bi2t[u] = wsf[P_BIH + (c*3+2)*kG + g];
    bh2t[u] = wsf[P_BHH + (c*3+2)*kG + g];
  }

  // fp32 elementwise GRU state: slot [i*2+th] = (cell q*4+i, hid th*16+ln)
  float h0s[8], h1s[8], h2s[8];
#pragma unroll
  for (int i = 0; i < 8; ++i) { h0s[i] = 0.f; h1s[i] = 0.f; h2s[i] = 0.f; }

  unsigned short* outsAll = (unsigned short*)wsf;
  unsigned short* outsC = outsAll + (size_t)(c*kB + b) * (kR*kS*kH);
  const unsigned short* outsP = outsAll + (size_t)(((c > 0 ? c : 1) - 1)*kB + b) * (kR*kS*kH);
  int* prog = (int*)(wsf + PROG_OFF);
  const int* xc = x + (b*3 + c) * kR * kS;
  const float* Tc = wsf + T_OFF + (size_t)c * kV * kG;

  __syncthreads();

  constexpr int DELTA = 2;
  const int TT = (kR + kS - 1) + 2*DELTA;
  for (int t = 0; t < TT; ++t) {
    const int d = t - c*DELTA;
    const bool wgact = (d >= 0) && (d < kR + kS - 1);

    if (c > 0 && wgact && tid == 0) {
      while (__hip_atomic_load(&prog[(c-1)*16 + b], __ATOMIC_ACQUIRE,
                               __HIP_MEMORY_SCOPE_AGENT) <= d) { }
    }
    __syncthreads();   // ring(d-1) complete + producer progress visible WG-wide

    if (wgact && d >= 16*w && d <= 16*w + 78) {
      // ---- cell metadata ----
      int rr[4], ssv[4], xi[4];
      bool act[4];
#pragma unroll
      for (int i = 0; i < 4; ++i) {
        int cell = q*4 + i;
        rr[i]  = 16*w + cell;
        ssv[i] = d - rr[i];
        act[i] = ((unsigned)ssv[i]) < 64u;
        int scl = ssv[i] < 0 ? 0 : (ssv[i] > 63 ? 63 : ssv[i]);
        xi[i] = xc[rr[i]*kS + scl];
      }
      const int pb = 1 - (d & 1);
      const int cb = d & 1;

      // ---- A-fragments ----
      bfrag phA, h2A, h0A, h1A, poA;
      {
        int pr = 16*w + m - 1;
        int prc = pr < 0 ? 0 : pr;
        phA = *(const bfrag*)&ring[pb][prc][q*8];
        if (pr < 0) {
#pragma unroll
          for (int j = 0; j < 8; ++j) phA[j] = 0;
        }
        h2A = *(const bfrag*)&ring[pb][16*w + m][q*8];
        if (m == d - 16*w) {           // this A-row's cell has s==0 -> no left neighbor
#pragma unroll
          for (int j = 0; j < 8; ++j) h2A[j] = 0;
        }
        h0A = *(const bfrag*)&h01[16*w + m][0][q*8];
        h1A = *(const bfrag*)&h01[16*w + m][1][q*8];
        if (c > 0) {
          int sA = d - (16*w + m);
          int sAc = sA < 0 ? 0 : (sA > 63 ? 63 : sA);
          poA = *(const bfrag*)&outsP[((size_t)(16*w + m)*kS + sAc)*kH + q*8];
        }
      }

      // ---- layer 0 ----
      ffrag gi0[6], gh0[6];
#pragma unroll
      for (int u = 0; u < 6; ++u) {
#pragma unroll
        for (int i = 0; i < 4; ++i) {
          float g = 0.f;
          if (act[i]) {
            float rp = (float)rr[i] * (2.0f/64.0f) - 1.0f;
            g = Tc[(size_t)xi[i]*kG + u*16 + ln] + rp*rwt[u] + c0t[u];
          }
          gi0[u][i] = g;
          gh0[u][i] = bh0t[u];
        }
      }
#pragma unroll
      for (int u = 0; u < 6; ++u)
        gi0[u] = __builtin_amdgcn_mfma_f32_16x16x32_bf16(phA, Wb[0][u], gi0[u], 0, 0, 0);
      if (c > 0) {
#pragma unroll
        for (int u = 0; u < 6; ++u)
          gi0[u] = __builtin_amdgcn_mfma_f32_16x16x32_bf16(poA, Wb[6][u], gi0[u], 0, 0, 0);
      }
#pragma unroll
      for (int u = 0; u < 6; ++u)
        gh0[u] = __builtin_amdgcn_mfma_f32_16x16x32_bf16(h0A, Wb[1][u], gh0[u], 0, 0, 0);

#pragma unroll
      for (int i = 0; i < 4; ++i) {
#pragma unroll
        for (int th = 0; th < 2; ++th) {
          float rg = sigm(gi0[th][i] + gh0[th][i]);
          float zg = sigm(gi0[2+th][i] + gh0[2+th][i]);
          float ng = tanh_(gi0[4+th][i] + rg*gh0[4+th][i]);
          float h0n = (1.f - zg)*ng + zg*h0s[i*2+th];
          if (act[i]) {
            h0s[i*2+th] = h0n;
            h01[rr[i]][0][th*16 + ln] = f2b(h0n);
          }
        }
      }
      bfrag h0An = *(const bfrag*)&h01[16*w + m][0][q*8];

      // ---- layer 1 ----
      ffrag gi1[6], gh1[6];
#pragma unroll
      for (int u = 0; u < 6; ++u) {
#pragma unroll
        for (int i = 0; i < 4; ++i) { gi1[u][i] = bi1t[u]; gh1[u][i] = bh1t[u]; }
      }
#pragma unroll
      for (int u = 0; u < 6; ++u) {
        gi1[u] = __builtin_amdgcn_mfma_f32_16x16x32_bf16(h0An, Wb[2][u], gi1[u], 0, 0, 0);
        gh1[u] = __builtin_amdgcn_mfma_f32_16x16x32_bf16(h1A,  Wb[3][u], gh1[u], 0, 0, 0);
      }
#pragma unroll
      for (int i = 0; i < 4; ++i) {
#pragma unroll
        for (int th = 0; th < 2; ++th) {
          float rg = sigm(gi1[th][i] + gh1[th][i]);
          float zg = sigm(gi1[2+th][i] + gh1[2+th][i]);
          float ng = tanh_(gi1[4+th][i] + rg*gh1[4+th][i]);
          float h1n = (1.f - zg)*ng + zg*h1s[i*2+th];
          if (act[i]) {
            h1s[i*2+th] = h1n;
            h01[rr[i]][1][th*16 + ln] = f2b(h1n);
          }
        }
      }
      bfrag h1An = *(const bfrag*)&h01[16*w + m][1][q*8];

      // ---- layer 2 ----
      ffrag gi2[6], gh2[6];
#pragma unroll
      for (int u = 0; u < 6; ++u) {
#pragma unroll
        for (int i = 0; i < 4; ++i) { gi2[u][i] = bi2t[u]; gh2[u][i] = bh2t[u]; }
      }
#pragma unroll
      for (int u = 0; u < 6; ++u) {
        gi2[u] = __builtin_amdgcn_mfma_f32_16x16x32_bf16(h1An, Wb[4][u], gi2[u], 0, 0, 0);
        gh2[u] = __builtin_amdgcn_mfma_f32_16x16x32_bf16(h2A,  Wb[5][u], gh2[u], 0, 0, 0);
      }
#pragma unroll
      for (int i = 0; i < 4; ++i) {
#pragma unroll
        for (int th = 0; th < 2; ++th) {
          float rg = sigm(gi2[th][i] + gh2[th][i]);
          float zg = sigm(gi2[2+th][i] + gh2[2+th][i]);
          float ng = tanh_(gi2[4+th][i] + rg*gh2[4+th][i]);
          float h2old = (ssv[i] == 0) ? 0.f : h2s[i*2+th];
          float h2n = (1.f - zg)*ng + zg*h2old;
          if (act[i]) {
            h2s[i*2+th] = h2n;
            short hb = f2b(h2n);
            ring[cb][rr[i]][th*16 + ln] = hb;
            outsC[((size_t)rr[i]*kS + ssv[i])*kH + th*16 + ln] = (unsigned short)hb;
          }
        }
      }
    }

    if (c < 2) __threadfence();   // per-wave vmcnt drain so outs are globally visible
    __syncthreads();              // all waves' ring(d)+outs(d) done
    if (wgact && c < 2 && tid == 0)
      __hip_atomic_store(&prog[c*16 + b], d + 1, __ATOMIC_RELEASE, __HIP_MEMORY_SCOPE_AGENT);
  }
}

// ---------------- logits epilogue (fp32 output, unchanged, verified) ----------------
__global__ void logits_kernel(const int* __restrict__ target, const float* __restrict__ wsf,
                              float* __restrict__ out)
{
  int idx = blockIdx.x * 256 + threadIdx.x;
  if (idx >= 3*kB*kR*kS*kV) return;
  int v = idx % kV;
  int pos = idx / kV;
  int g = pos >> 12;
  int ch = g % 3;
  int b = g / 3;
  int rs = pos & 4095;
  const bf16* hv = (const bf16*)wsf + ((size_t)(ch*kB + b)*4096 + rs)*kH;
  float acc;
  const float* wv;
  if (ch == 0) {
    acc = wsf[P_REDB + v];
    wv = wsf + P_REDW + v*kH;
  } else if (ch == 1) {
    int tr = target[(b*3 + 0)*4096 + rs];
    acc = wsf[P_GREENB + v] + wsf[TG_OFF + tr*kV + v];
    wv = wsf + P_GREENW + v*(kH + kE);
  } else {
    int tr = target[(b*3 + 0)*4096 + rs];
    int tg = target[(b*3 + 1)*4096 + rs];
    acc = wsf[P_BLUEB + v] + wsf[TBR_OFF + tr*kV + v] + wsf[TBG_OFF + tg*kV + v];
    wv = wsf + P_BLUEW + v*(kH + 2*kE);
  }
#pragma unroll
  for (int k = 0; k < kH; ++k) acc = fmaf(wv[k], tof(hv[k]), acc);
  out[idx] = acc;
}

extern "C" void kernel_launch(void* const* d_in, const int* in_sizes, int n_in,
                              void* d_out, int out_size, void* d_ws, size_t ws_size,
                              hipStream_t stream)
{
  const int* x      = (const int*)d_in[0];
  const int* target = (const int*)d_in[1];
  float* wsf = (float*)d_ws;

  norm_kernel<<<16, 256, 0, stream>>>(d_in[2], d_in[3], d_in[4], d_in[5], d_in[6], d_in[7],
                                      d_in[8], d_in[9], d_in[10], d_in[11], d_in[12], d_in[13],
                                      d_in[14], d_in[15], d_in[16], d_in[17], wsf);
  const int prepN = 3*kV*kG + 3*kG*kH + 2*kG*kH + 3*kG + 3*kG + 3*kV*kV;
  prep_kernel<<<(prepN + 255)/256, 256, 0, stream>>>(wsf);
  recur_all_kernel<<<48, 256, 0, stream>>>(x, wsf);
  const int outN = 3*kB*kR*kS*kV;
  logits_kernel<<<(outN + 255)/256, 256, 0, stream>>>(target, wsf, (float*)d_out);
}